// Round 2
// baseline (730.730 us; speedup 1.0000x reference)
//
#include <hip/hip_runtime.h>

// ---------------------------------------------------------------------------
// Fused 3x3 valid conv (64->128) + bias + *2 + min over oc, single kernel.
// Implicit GEMM, mfma_f32_16x16x32_bf16. Block 512 thr (8 waves), tile
// 32W x 16H x 128oc, wave tile 4M x 8N (acc 128 VGPR).
// K = 576 = 2 ic-chunks x 9 taps x K32.
// LDS (152,064 B): x bf16 [2 buf][18row][34col][32ic, 16B-octet XOR-swizzled
//   by col&3 -> conflict-free frag reads AND staging writes, exact stride],
//   W bf16 [128oc][9tap*32ic, octet swizzled by oc&3], staged per chunk
//   in-kernel from fp32 w (L2-resident, no repack kernel / no d_ws).
// Pipeline: stage x0+W0 | bar | issue x1 global loads -> regs | compute c0
//   | bar | convert+write x1, stage W1 | bar | compute c1 | min-epilogue.
// ---------------------------------------------------------------------------

#define TW 32
#define TH 16
#define XROWS 18
#define XCOLS 34
#define XTILE (XROWS * XCOLS * 32)           // 19584 shorts per buffer
#define WSTR 288
#define WTILE (128 * WSTR)                   // 36864 shorts
#define LDS_BYTES ((2 * XTILE + WTILE) * 2)  // 152064 B

typedef __attribute__((ext_vector_type(8))) short short8;
typedef __attribute__((ext_vector_type(4))) float f32x4;
typedef __attribute__((ext_vector_type(4))) float f4;
typedef __attribute__((ext_vector_type(2))) float f2;

__device__ __forceinline__ unsigned short f2bf(float f) {
  unsigned int u = __builtin_bit_cast(unsigned int, f);
  u += 0x7FFFu + ((u >> 16) & 1u);  // round-to-nearest-even
  return (unsigned short)(u >> 16);
}
__device__ __forceinline__ unsigned int pk2(float lo, float hi) {
  return (unsigned int)f2bf(lo) | ((unsigned int)f2bf(hi) << 16);
}

// x LDS put: logical (row, col, ic-pair) -> octet-swizzled address.
__device__ __forceinline__ void xput(unsigned short* xs, int row, int col,
                                     int pair, unsigned int pk) {
  int off = (row * XCOLS + col) * 32 + (((pair >> 2) ^ (col & 3)) << 3) +
            (pair & 3) * 2;
  *(unsigned int*)&xs[off] = pk;
}

__device__ __forceinline__ void stage_w(const float* __restrict__ w,
                                        unsigned short* wl, int c, int tid) {
  // w fp32 [oc][ic64][3][3]; chunk c = ic [c*32, c*32+32) = 288 contiguous
  // floats per oc. LDS layout [oc][tap][ic32] with octet ^ (oc&3) swizzle.
  for (int i = tid; i < 18432; i += 512) {
    int oc = i / 144;
    int r  = (i - oc * 144) * 2;
    f2 v = *(const f2*)(w + oc * 576 + c * 288 + r);
#pragma unroll
    for (int e = 0; e < 2; ++e) {
      int idx = r + e;
      int tap = idx % 9, icn = idx / 9;
      wl[oc * WSTR + tap * 32 + (((icn >> 3) ^ (oc & 3)) << 3) + (icn & 7)] =
          f2bf(v[e]);
    }
  }
}

__device__ __forceinline__ void compute_chunk(const unsigned short* xsb,
                                              const unsigned short* wl,
                                              f32x4 acc[4][8], int wv, int q,
                                              int cl) {
#pragma unroll
  for (int tap = 0; tap < 9; ++tap) {
    const int kh = tap / 3, kw = tap % 3;
    short8 af[4];
#pragma unroll
    for (int j = 0; j < 4; ++j) {
      int t  = wv * 4 + j;
      int hr = (t >> 1) + kh;
      int cc = (t & 1) * 16 + cl + kw;
      af[j] = *(const short8*)&xsb[(hr * XCOLS + cc) * 32 +
                                   ((q ^ (cc & 3)) << 3)];
    }
    short8 bf8[8];
#pragma unroll
    for (int n = 0; n < 8; ++n) {
      int oc = n * 16 + cl;
      bf8[n] = *(const short8*)&wl[oc * WSTR + tap * 32 +
                                   ((q ^ (cl & 3)) << 3)];
    }
#pragma unroll
    for (int j = 0; j < 4; ++j)
#pragma unroll
      for (int n = 0; n < 8; ++n)
        acc[j][n] = __builtin_amdgcn_mfma_f32_16x16x32_bf16(af[j], bf8[n],
                                                            acc[j][n], 0, 0, 0);
  }
}

__global__ __launch_bounds__(512, 2) void conv_min_kernel(
    const float* __restrict__ x, const float* __restrict__ w,
    const float* __restrict__ bias, float* __restrict__ out) {
  extern __shared__ unsigned short lds[];
  unsigned short* xs = lds;               // [2][XTILE]
  unsigned short* wl = lds + 2 * XTILE;   // [WTILE]

  const int tid  = threadIdx.x;
  const int wv   = tid >> 6;
  const int lane = tid & 63;
  const int q    = lane >> 4;
  const int cl   = lane & 15;

  const int W0 = blockIdx.x * TW;
  const int H0 = blockIdx.y * TH;
  const int b  = blockIdx.z;
  const float* xb = x + (size_t)b * 64 * 65536;

  f32x4 acc[4][8];
#pragma unroll
  for (int j = 0; j < 4; ++j)
#pragma unroll
    for (int n = 0; n < 8; ++n) acc[j][n] = (f32x4){0.f, 0.f, 0.f, 0.f};

  // ---- stage chunk 0: x -> xs[0] (load->convert->write), W0 -> wl ----
  // Vector part: 18 rows x 8 col-groups(4) x 16 ic-pairs = 2304 items.
  // gc = W0 + colg*4 + 3 <= 224+28+3 = 255: always in-bounds, 16B aligned.
  for (int i = tid; i < 2304; i += 512) {
    int pair = i & 15, colg = (i >> 4) & 7, row = i >> 7;
    int gr = min(H0 + row, 255);  // clamped rows never feed stored outputs
    const float* p = xb + (size_t)(pair * 2) * 65536 + gr * 256 + W0 + colg * 4;
    f4 a = *(const f4*)p;
    f4 c = *(const f4*)(p + 65536);
#pragma unroll
    for (int e = 0; e < 4; ++e)
      xput(xs, row, colg * 4 + e, pair, pk2(a[e], c[e]));
  }
  // Ragged cols 32,33: 18 rows x 2 cols x 16 pairs = 576 items (col clamp).
  for (int i = tid; i < 576; i += 512) {
    int pair = i & 15, cole = (i >> 4) & 1, row = i >> 5;
    int col = 32 + cole;
    int gr = min(H0 + row, 255), gc = min(W0 + col, 255);
    const float* p = xb + (size_t)(pair * 2) * 65536 + gr * 256 + gc;
    xput(xs, row, col, pair, pk2(p[0], p[65536]));
  }
  stage_w(w, wl, 0, tid);
  __syncthreads();

  // ---- issue chunk-1 x global loads into registers (latency hidden by c0)
  f4 pfa[5], pfb[5];
  float pr0[2], pr1[2];
#pragma unroll
  for (int k = 0; k < 5; ++k) {
    int i = tid + k * 512;
    if (i < 2304) {
      int pair = i & 15, colg = (i >> 4) & 7, row = i >> 7;
      int gr = min(H0 + row, 255);
      const float* p =
          xb + (size_t)(32 + pair * 2) * 65536 + gr * 256 + W0 + colg * 4;
      pfa[k] = *(const f4*)p;
      pfb[k] = *(const f4*)(p + 65536);
    }
  }
#pragma unroll
  for (int k = 0; k < 2; ++k) {
    int i = tid + k * 512;
    if (i < 576) {
      int pair = i & 15, cole = (i >> 4) & 1, row = i >> 5;
      int gr = min(H0 + row, 255), gc = min(W0 + 32 + cole, 255);
      const float* p = xb + (size_t)(32 + pair * 2) * 65536 + gr * 256 + gc;
      pr0[k] = p[0];
      pr1[k] = p[65536];
    }
  }

  compute_chunk(xs, wl, acc, wv, q, cl);
  __syncthreads();  // all waves done reading W chunk 0 (and xs[0])

  // ---- write prefetched chunk-1 x -> xs[1]; restage W1 ----
#pragma unroll
  for (int k = 0; k < 5; ++k) {
    int i = tid + k * 512;
    if (i < 2304) {
      int pair = i & 15, colg = (i >> 4) & 7, row = i >> 7;
#pragma unroll
      for (int e = 0; e < 4; ++e)
        xput(xs + XTILE, row, colg * 4 + e, pair, pk2(pfa[k][e], pfb[k][e]));
    }
  }
#pragma unroll
  for (int k = 0; k < 2; ++k) {
    int i = tid + k * 512;
    if (i < 576) {
      int pair = i & 15, cole = (i >> 4) & 1, row = i >> 5;
      xput(xs + XTILE, row, 32 + cole, pair, pk2(pr0[k], pr1[k]));
    }
  }
  stage_w(w, wl, 1, tid);
  __syncthreads();

  compute_chunk(xs + XTILE, wl, acc, wv, q, cl);

  // ---- epilogue: (acc + bias)*2, min over 128 oc, shuffle-reduce, store ----
  float bv[8];
#pragma unroll
  for (int n = 0; n < 8; ++n) bv[n] = bias[n * 16 + cl];

#pragma unroll
  for (int j = 0; j < 4; ++j) {
    int t   = wv * 4 + j;
    int oh  = H0 + (t >> 1);
    int owb = W0 + (t & 1) * 16;
    float mn[4] = {INFINITY, INFINITY, INFINITY, INFINITY};
#pragma unroll
    for (int n = 0; n < 8; ++n)
#pragma unroll
      for (int r = 0; r < 4; ++r)
        mn[r] = fminf(mn[r], (acc[j][n][r] + bv[n]) * 2.0f);
#pragma unroll
    for (int r = 0; r < 4; ++r) {
      mn[r] = fminf(mn[r], __shfl_xor(mn[r], 1));
      mn[r] = fminf(mn[r], __shfl_xor(mn[r], 2));
      mn[r] = fminf(mn[r], __shfl_xor(mn[r], 4));
      mn[r] = fminf(mn[r], __shfl_xor(mn[r], 8));
      int m  = q * 4 + r;  // C/D: row = quad*4 + reg, col = lane&15
      int ow = owb + m;
      if (cl == m && oh < 254 && ow < 254)
        out[((size_t)b * 254 + oh) * 254 + ow] = mn[r];
    }
  }
}

extern "C" void kernel_launch(void* const* d_in, const int* in_sizes, int n_in,
                              void* d_out, int out_size, void* d_ws,
                              size_t ws_size, hipStream_t stream) {
  const float* x    = (const float*)d_in[0];
  const float* w    = (const float*)d_in[1];
  const float* bias = (const float*)d_in[2];
  float* out        = (float*)d_out;

  hipFuncSetAttribute(reinterpret_cast<const void*>(conv_min_kernel),
                      hipFuncAttributeMaxDynamicSharedMemorySize, LDS_BYTES);

  dim3 grid(8, 16, 16);  // ceil(254/32), ceil(254/16), batch
  conv_min_kernel<<<grid, 512, LDS_BYTES, stream>>>(x, w, bias, out);
}

// Round 3
// 553.580 us; speedup vs baseline: 1.3200x; 1.3200x over previous
//
#include <hip/hip_runtime.h>

// ---------------------------------------------------------------------------
// Fused 3x3 valid conv (64->128) + bias + *2 + min over oc.
// Implicit GEMM, mfma_f32_16x16x32_bf16.
// Block: 256 thr (4 waves), tile 16H x 16W x 128 oc. Wave: 4 M-tiles
// (M-tile = one output row; m = col) x 8 N-tiles (acc 128 regs -> AGPRs).
// K = 576 split as [2 ic-chunks of 32] x [3 kh-groups] x [3 kw taps, K=32].
// LDS 45,312 B (2 blocks/CU, VGPR-capped):
//   xs [18 row][18 col][32 ic] bf16, 16B-octet XOR swizzle by (col>>1)&3
//   wl [3 tt][128 oc][32 ic]  bf16, octet swizzle by (oc>>1)&3 (pre-applied
//      in ws by repack kernel; LDS stage is a linear uint4 copy)
// Overlap comes from 2 co-resident blocks (R2 lesson: register prefetch
// spills against a 128-reg acc tile -> 296MB scratch traffic).
// ---------------------------------------------------------------------------

#define XR 18
#define XC 18
#define XTILE_SH (XR * XC * 32)   // 10368 shorts = 20736 B
#define WG_SH (3 * 128 * 32)      // 12288 shorts = 24576 B

typedef __attribute__((ext_vector_type(8))) short short8;
typedef __attribute__((ext_vector_type(4))) float f32x4;

__device__ __forceinline__ unsigned short f2bf(float f) {
  unsigned int u = __builtin_bit_cast(unsigned int, f);
  u += 0x7FFFu + ((u >> 16) & 1u);  // round-to-nearest-even
  return (unsigned short)(u >> 16);
}
__device__ __forceinline__ unsigned int pk2(float lo, float hi) {
  return (unsigned int)f2bf(lo) | ((unsigned int)f2bf(hi) << 16);
}

// W fp32 [oc][ic64][kh][kw] -> ws bf16 [c*3+g][tt][oc][octet^((oc>>1)&3)][8]
__global__ void repack_w(const float* __restrict__ w,
                         unsigned short* __restrict__ ws) {
  int e = blockIdx.x * 256 + threadIdx.x;  // 73728 exact
  int s    = e & 7;
  int osw  = (e >> 3) & 3;
  int oc   = (e >> 5) & 127;
  int rest = e >> 12;          // 0..17 = cg*3 + tt
  int tt   = rest % 3;
  int cg   = rest / 3;         // c*3 + g
  int c = cg / 3, g = cg % 3;
  int o  = osw ^ ((oc >> 1) & 3);
  int ic = c * 32 + o * 8 + s;
  ws[e] = f2bf(w[oc * 576 + ic * 9 + g * 3 + tt]);
}

__global__ __launch_bounds__(256, 2) void conv_min_kernel(
    const float* __restrict__ x, const unsigned short* __restrict__ ws,
    const float* __restrict__ bias, float* __restrict__ out) {
  __shared__ unsigned short xs[XTILE_SH];
  __shared__ unsigned short wl[WG_SH];

  const int tid  = threadIdx.x;
  const int wv   = tid >> 6;
  const int lane = tid & 63;
  const int q    = lane >> 4;
  const int cl   = lane & 15;

  const int W0 = blockIdx.x * 16;
  const int H0 = blockIdx.y * 16;
  const int b  = blockIdx.z;
  const float* xb = x + (size_t)b * 64 * 65536;

  f32x4 acc[4][8];
#pragma unroll
  for (int j = 0; j < 4; ++j)
#pragma unroll
    for (int n = 0; n < 8; ++n) acc[j][n] = (f32x4){0.f, 0.f, 0.f, 0.f};

  for (int c = 0; c < 2; ++c) {
#pragma unroll 1
    for (int g = 0; g < 3; ++g) {
      if (c + g) __syncthreads();  // prior compute done reading wl (and xs)

      if (g == 0) {
        // ---- stage x ic-chunk c: 18 rows x 9 col-pairs x 16 ic-pairs ----
        for (int i = tid; i < 2592; i += 256) {
          int pair = i & 15, r2 = i >> 4;
          int cp = r2 % 9, row = r2 / 9;
          int gr = min(H0 + row, 255);       // clamped rows/cols feed only
          int gc = min(W0 + 2 * cp, 254);    // discarded outputs
          const float* p =
              xb + (size_t)(c * 32 + pair * 2) * 65536 + gr * 256 + gc;
          float2 a = *(const float2*)p;
          float2 d = *(const float2*)(p + 65536);
          int base = ((row * XC + 2 * cp) << 5) +
                     ((((pair >> 2) ^ (cp & 3)) << 3) + ((pair & 3) << 1));
          *(unsigned int*)&xs[base]      = pk2(a.x, d.x);
          *(unsigned int*)&xs[base + 32] = pk2(a.y, d.y);
        }
      }

      // ---- stage W group (c,g): linear coalesced uint4 copy ----
      {
        const uint4* src = (const uint4*)(ws + (c * 3 + g) * WG_SH);
        uint4* dst = (uint4*)wl;
        for (int i = tid; i < WG_SH / 8; i += 256) dst[i] = src[i];
      }
      __syncthreads();

      // ---- compute: kh = g, 3 kw taps, K=32 each ----
#pragma unroll
      for (int tt = 0; tt < 3; ++tt) {
        short8 bf8[8];
#pragma unroll
        for (int n = 0; n < 8; ++n) {
          int oc = n * 16 + cl;
          bf8[n] = *(const short8*)&wl[((tt * 128 + oc) << 5) +
                                       ((q ^ ((oc >> 1) & 3)) << 3)];
        }
#pragma unroll
        for (int j = 0; j < 4; ++j) {
          int t    = wv * 4 + j;
          int colx = cl + tt;
          short8 af = *(const short8*)&xs[(((t + g) * XC + colx) << 5) +
                                          ((q ^ ((colx >> 1) & 3)) << 3)];
#pragma unroll
          for (int n = 0; n < 8; ++n)
            acc[j][n] = __builtin_amdgcn_mfma_f32_16x16x32_bf16(
                af, bf8[n], acc[j][n], 0, 0, 0);
        }
      }
    }
  }

  // ---- epilogue: (acc + bias)*2, min over 128 oc, store ----
  float bv[8];
#pragma unroll
  for (int n = 0; n < 8; ++n) bv[n] = bias[n * 16 + cl];

#pragma unroll
  for (int j = 0; j < 4; ++j) {
    int t  = wv * 4 + j;
    int oh = H0 + t;
    float mn[4] = {INFINITY, INFINITY, INFINITY, INFINITY};
#pragma unroll
    for (int n = 0; n < 8; ++n)
#pragma unroll
      for (int r = 0; r < 4; ++r)
        mn[r] = fminf(mn[r], (acc[j][n][r] + bv[n]) * 2.0f);
#pragma unroll
    for (int r = 0; r < 4; ++r) {
      mn[r] = fminf(mn[r], __shfl_xor(mn[r], 1));
      mn[r] = fminf(mn[r], __shfl_xor(mn[r], 2));
      mn[r] = fminf(mn[r], __shfl_xor(mn[r], 4));
      mn[r] = fminf(mn[r], __shfl_xor(mn[r], 8));
      int m  = q * 4 + r;  // C/D: row(m) = quad*4 + reg, col(n) = lane&15
      int ow = W0 + m;
      if (cl == m && oh < 254 && ow < 254)
        out[((size_t)b * 254 + oh) * 254 + ow] = mn[r];
    }
  }
}

extern "C" void kernel_launch(void* const* d_in, const int* in_sizes, int n_in,
                              void* d_out, int out_size, void* d_ws,
                              size_t ws_size, hipStream_t stream) {
  const float* x    = (const float*)d_in[0];
  const float* w    = (const float*)d_in[1];
  const float* bias = (const float*)d_in[2];
  float* out        = (float*)d_out;
  unsigned short* ws = (unsigned short*)d_ws;  // 147,456 B bf16 weights

  // ws re-poisoned before every call -> repack every call (same work/call).
  repack_w<<<288, 256, 0, stream>>>(w, ws);

  dim3 grid(16, 16, 16);  // 16x16 tiles over 254x254, batch 16
  conv_min_kernel<<<grid, 256, 0, stream>>>(x, ws, bias, out);
}

// Round 4
// 526.086 us; speedup vs baseline: 1.3890x; 1.0523x over previous
//
#include <hip/hip_runtime.h>

// ---------------------------------------------------------------------------
// Fused 3x3 valid conv (64->128) + bias + *2 + min over oc.
// Implicit GEMM, mfma_f32_16x16x32_bf16.
// Block: 256 thr (4 waves), tile 16H x 16W x 128 oc. Wave: 4 M-tiles
// (M-tile = one output row; m = col) x 8 N-tiles (acc 128 regs -> AGPRs).
// K = 576 split as [2 ic-chunks of 32] x [3 kh-groups] x [3 kw taps, K=32].
// LDS 45,312 B:
//   xs [18 row][18 col][32 ic] bf16, octet swizzle (pair>>2)^((col>>1)&3)^(row&3)
//   wl [3 tt][128 oc][32 ic]  bf16, octet swizzle (oc>>1)&3 (pre-applied in ws)
// R3 lesson: staging loads MUST be px-major — lane-major-over-ic put 64 lanes
// on 64 different 128KB-strided planes (≈64 transactions/inst, TA-bound at
// ~20% on every visible pipe). Here lane quads cover exactly one 64B line.
// R2 lesson: no register prefetch against a 128-reg acc tile (spills).
// ---------------------------------------------------------------------------

#define XR 18
#define XC 18
#define XTILE_SH (XR * XC * 32)   // 10368 shorts = 20736 B
#define WG_SH (3 * 128 * 32)      // 12288 shorts = 24576 B

typedef __attribute__((ext_vector_type(8))) short short8;
typedef __attribute__((ext_vector_type(4))) float f32x4;
typedef __attribute__((ext_vector_type(4))) float f4;

__device__ __forceinline__ unsigned short f2bf(float f) {
  unsigned int u = __builtin_bit_cast(unsigned int, f);
  u += 0x7FFFu + ((u >> 16) & 1u);  // round-to-nearest-even
  return (unsigned short)(u >> 16);
}
__device__ __forceinline__ unsigned int pk2(float lo, float hi) {
  return (unsigned int)f2bf(lo) | ((unsigned int)f2bf(hi) << 16);
}

// x LDS put: (row, col, ic-pair) -> swizzled dword address.
__device__ __forceinline__ void xput(unsigned short* xs, int row, int col,
                                     int pair, unsigned int pk) {
  int o = ((pair >> 2) ^ ((col >> 1) & 3) ^ (row & 3));
  int off = ((row * XC + col) << 5) + (o << 3) + ((pair & 3) << 1);
  *(unsigned int*)&xs[off] = pk;
}

// W fp32 [oc][ic64][kh][kw] -> ws bf16 [c*3+g][tt][oc][octet^((oc>>1)&3)][8]
__global__ void repack_w(const float* __restrict__ w,
                         unsigned short* __restrict__ ws) {
  int e = blockIdx.x * 256 + threadIdx.x;  // 73728 exact
  int s    = e & 7;
  int osw  = (e >> 3) & 3;
  int oc   = (e >> 5) & 127;
  int rest = e >> 12;          // 0..17 = cg*3 + tt
  int tt   = rest % 3;
  int cg   = rest / 3;         // c*3 + g
  int c = cg / 3, g = cg % 3;
  int o  = osw ^ ((oc >> 1) & 3);
  int ic = c * 32 + o * 8 + s;
  ws[e] = f2bf(w[oc * 576 + ic * 9 + g * 3 + tt]);
}

__global__ __launch_bounds__(256, 2) void conv_min_kernel(
    const float* __restrict__ x, const unsigned short* __restrict__ ws,
    const float* __restrict__ bias, float* __restrict__ out) {
  __shared__ unsigned short xs[XTILE_SH];
  __shared__ unsigned short wl[WG_SH];

  const int tid  = threadIdx.x;
  const int wv   = tid >> 6;
  const int lane = tid & 63;
  const int q    = lane >> 4;
  const int cl   = lane & 15;

  const int W0 = blockIdx.x * 16;
  const int H0 = blockIdx.y * 16;
  const int b  = blockIdx.z;
  const float* xb = x + (size_t)b * 64 * 65536;

  f32x4 acc[4][8];
#pragma unroll
  for (int j = 0; j < 4; ++j)
#pragma unroll
    for (int n = 0; n < 8; ++n) acc[j][n] = (f32x4){0.f, 0.f, 0.f, 0.f};

  for (int c = 0; c < 2; ++c) {
#pragma unroll 1
    for (int g = 0; g < 3; ++g) {
      if (c + g) __syncthreads();  // prior compute done reading wl (and xs)

      if (g == 0) {
        // ---- stage x ic-chunk c, px-major (coalesced) ----
        // Main: 16 ic-pairs x 18 rows x 4 col-groups = 1152 float4 items.
        // Lane quads (g4 0..3) cover one aligned 64B line per row.
        for (int i = tid; i < 1152; i += 256) {
          int g4   = i & 3;
          int r2   = i >> 2;            // pair*18 + row
          int row  = r2 % 18;
          int pair = r2 / 18;
          int gr = min(H0 + row, 255);  // clamped rows feed only discarded oh
          const float* p =
              xb + (size_t)(c * 32 + pair * 2) * 65536 + gr * 256 + W0 + g4 * 4;
          f4 a = *(const f4*)p;
          f4 d = *(const f4*)(p + 65536);
#pragma unroll
          for (int e = 0; e < 4; ++e)
            xput(xs, row, g4 * 4 + e, pair, pk2(a[e], d[e]));
        }
        // Ragged cols 16,17: 16 pairs x 18 rows (col-clamped: clamped data
        // feeds only ow >= 254, which is never stored).
        for (int i = tid; i < 288; i += 256) {
          int row = i % 18, pair = i / 18;
          int gr = min(H0 + row, 255);
          int gc = min(W0 + 16, 254);
          const float* p =
              xb + (size_t)(c * 32 + pair * 2) * 65536 + gr * 256 + gc;
          float2 a = *(const float2*)p;
          float2 d = *(const float2*)(p + 65536);
          xput(xs, row, 16, pair, pk2(a.x, d.x));
          xput(xs, row, 17, pair, pk2(a.y, d.y));
        }
      }

      // ---- stage W group (c,g): linear coalesced uint4 copy ----
      {
        const uint4* src = (const uint4*)(ws + (c * 3 + g) * WG_SH);
        uint4* dst = (uint4*)wl;
        for (int i = tid; i < WG_SH / 8; i += 256) dst[i] = src[i];
      }
      __syncthreads();

      // ---- compute: kh = g, 3 kw taps, K=32 each ----
#pragma unroll
      for (int tt = 0; tt < 3; ++tt) {
        short8 bf8[8];
#pragma unroll
        for (int n = 0; n < 8; ++n) {
          int oc = n * 16 + cl;
          bf8[n] = *(const short8*)&wl[((tt * 128 + oc) << 5) +
                                       ((q ^ ((oc >> 1) & 3)) << 3)];
        }
#pragma unroll
        for (int j = 0; j < 4; ++j) {
          int t    = wv * 4 + j;
          int rowx = t + g;
          int colx = cl + tt;
          short8 af = *(const short8*)&xs[((rowx * XC + colx) << 5) +
                                          ((q ^ ((colx >> 1) & 3) ^
                                            (rowx & 3)) << 3)];
#pragma unroll
          for (int n = 0; n < 8; ++n)
            acc[j][n] = __builtin_amdgcn_mfma_f32_16x16x32_bf16(
                af, bf8[n], acc[j][n], 0, 0, 0);
        }
      }
    }
  }

  // ---- epilogue: (acc + bias)*2, min over 128 oc, store ----
  float bv[8];
#pragma unroll
  for (int n = 0; n < 8; ++n) bv[n] = bias[n * 16 + cl];

#pragma unroll
  for (int j = 0; j < 4; ++j) {
    int t  = wv * 4 + j;
    int oh = H0 + t;
    float mn[4] = {INFINITY, INFINITY, INFINITY, INFINITY};
#pragma unroll
    for (int n = 0; n < 8; ++n)
#pragma unroll
      for (int r = 0; r < 4; ++r)
        mn[r] = fminf(mn[r], (acc[j][n][r] + bv[n]) * 2.0f);
#pragma unroll
    for (int r = 0; r < 4; ++r) {
      mn[r] = fminf(mn[r], __shfl_xor(mn[r], 1));
      mn[r] = fminf(mn[r], __shfl_xor(mn[r], 2));
      mn[r] = fminf(mn[r], __shfl_xor(mn[r], 4));
      mn[r] = fminf(mn[r], __shfl_xor(mn[r], 8));
      int m  = q * 4 + r;  // C/D: row(m) = quad*4 + reg, col(n) = lane&15
      int ow = W0 + m;
      if (cl == m && oh < 254 && ow < 254)
        out[((size_t)b * 254 + oh) * 254 + ow] = mn[r];
    }
  }
}

extern "C" void kernel_launch(void* const* d_in, const int* in_sizes, int n_in,
                              void* d_out, int out_size, void* d_ws,
                              size_t ws_size, hipStream_t stream) {
  const float* x    = (const float*)d_in[0];
  const float* w    = (const float*)d_in[1];
  const float* bias = (const float*)d_in[2];
  float* out        = (float*)d_out;
  unsigned short* ws = (unsigned short*)d_ws;  // 147,456 B bf16 weights

  // ws re-poisoned before every call -> repack every call (same work/call).
  repack_w<<<288, 256, 0, stream>>>(w, ws);

  dim3 grid(16, 16, 16);  // 16x16 tiles over 254x254, batch 16
  conv_min_kernel<<<grid, 256, 0, stream>>>(x, ws, bias, out);
}